// Round 18
// baseline (166.586 us; speedup 1.0000x reference)
//
#include <hip/hip_runtime.h>
#include <hip/hip_fp16.h>

// Tree NN: reps = emb[tokens] (4096 x 128 x 128); 7x: reps = tanh(concat(pairs) @ W_tree^T + b);
// out = root @ W_cls^T + b_cls.
//
// R18 = R13 + round-balancing at 4 blocks/CU. Makespan audit: each CU owns 8 pairs; at
// 3 blocks/CU that is ceil(8/3)=3 latency-bound rounds, the 3rd only 2/3 occupied (~9us
// waste). Fix: LDS 53.2 -> 35.9 KB (bufA halved: gather+L0 split into two 64-leaf halves,
// ga->rows 0-31 / L0a->bufB 0-15, gb overwrites / L0b->bufB 16-31) so the HW fits
// 4 blocks/CU; grid 1024 = 4/CU x exactly 2 pairs -> 2 balanced rounds. KEY: keep
// lb(256,3) -- R10 failed only because lb(256,4) cut the VGPR cap to 64 (spill); the 2nd
// arg is a minimum, residency is resource-determined. Cost: 18 sections/pair (was 14).
// Tripwires: WRITE_SIZE in MBs = spill; OccupancyPercent ~29 = 4-residency failed -> R13.
//
// Wave w owns output n-tiles {2w,2w+1} at every level (Wf[2][8] = 64 VGPR, the proven
// no-spill maximum). Pair-contiguous LDS layout (concat free); conflict-free gather
// writes; token preloads one section ahead; pair-batched L5/L6 tail; K-split MFMA.
// fp16 MFMA 16x16x32, fp32 accumulate/tanh/classifier. absmax 3.9e-3 (thr 2.1e-2).

typedef _Float16 half8 __attribute__((ext_vector_type(8)));
typedef float floatx4 __attribute__((ext_vector_type(4)));

#define STRIDE 264   // 256 + 8 fp16 pad: A-row ds_read_b128 conflict-free
#define UROW   33    // uint4 per row
#define NPAIR  2048

__device__ __forceinline__ float fast_tanh(float x) {
  // No clamp needed: e=inf -> 1; e=0 -> -1. Inputs never NaN.
  float e = __expf(2.f * x);
  return 1.f - 2.f * __builtin_amdgcn_rcpf(e + 1.f);
}

__device__ __forceinline__ unsigned pkrtz(float a, float b) {
  auto h = __builtin_amdgcn_cvt_pkrtz(a, b);   // __fp16 ext_vector(2)
  return __builtin_bit_cast(unsigned, h);
}

// Gather one 64-leaf half into bufA rows 0-31. Thread (row=t&31, seg=t>>5) covers leaf
// 2*row+(seg>>2) of the half, feature quarter (seg&3)*32. Writes 4 uint4 at
// row*33 + (seg>>2)*16 + (seg&3)*4: lanes 0-31 hit 32 distinct rows (33 mod 8 cycling)
// -> conflict-free write phases.
__device__ __forceinline__ void gather_half(int tok, const float* __restrict__ emb,
                                            _Float16* buf, int row, int seg) {
  const float4* src = (const float4*)emb + (size_t)tok * 32 + (seg & 3) * 8;
  uint4* dst = (uint4*)buf + row * UROW + (seg >> 2) * 16 + (seg & 3) * 4;
#pragma unroll
  for (int j = 0; j < 4; ++j) {
    float4 x = src[2 * j], y = src[2 * j + 1];
    uint4 w;
    w.x = pkrtz(x.x, x.y); w.y = pkrtz(x.z, x.w);
    w.z = pkrtz(y.x, y.y); w.w = pkrtz(y.z, y.w);
    dst[j] = w;
  }
}

// K=256 MFMA for one 16-row m-tile, 2 n-tiles, K-split into 2 independent 4-chains.
// A-frag: A[m=lane&15][k=quad*8+j]; B-frag: B[k=quad*8+j][n=lane&15];
// D: col=lane&15, row=quad*4+reg (verified layouts, learn_hip m89/m91).
__device__ __forceinline__ void mfma_k256(const _Float16* arow, const half8 (&Wf)[2][8],
                                          floatx4 (&accO)[2]) {
  floatx4 aA[2], aB[2];
  aA[0] = (floatx4){0.f, 0.f, 0.f, 0.f}; aA[1] = (floatx4){0.f, 0.f, 0.f, 0.f};
  aB[0] = (floatx4){0.f, 0.f, 0.f, 0.f}; aB[1] = (floatx4){0.f, 0.f, 0.f, 0.f};
#pragma unroll
  for (int ks = 0; ks < 4; ++ks) {
    half8 x0 = *(const half8*)(arow + ks * 32);
    half8 x1 = *(const half8*)(arow + (ks + 4) * 32);
    aA[0] = __builtin_amdgcn_mfma_f32_16x16x32_f16(x0, Wf[0][ks],     aA[0], 0, 0, 0);
    aB[0] = __builtin_amdgcn_mfma_f32_16x16x32_f16(x1, Wf[0][ks + 4], aB[0], 0, 0, 0);
    aA[1] = __builtin_amdgcn_mfma_f32_16x16x32_f16(x0, Wf[1][ks],     aA[1], 0, 0, 0);
    aB[1] = __builtin_amdgcn_mfma_f32_16x16x32_f16(x1, Wf[1][ks + 4], aB[1], 0, 0, 0);
  }
  accO[0] = aA[0] + aB[0];
  accO[1] = aA[1] + aB[1];
}

// One wave: its 2 n-tiles for MT m-tiles; local-node pair-contiguous store
// (row = node>>1 relative to outb), MOUT row mask. Stale input rows are finite; masked.
template<int MT, int MOUT>
__device__ __forceinline__ void level_std(
    const _Float16* inb, _Float16* outb,
    const half8 (&Wf)[2][8], const float (&bias)[2],
    int nbase, int l15, int quad)
{
  floatx4 acc[MT][2];
  if (MT == 1) {
    floatx4 a2[2];
    mfma_k256(inb + l15 * STRIDE + quad * 8, Wf, a2);
    acc[0][0] = a2[0]; acc[0][1] = a2[1];
  } else {
#pragma unroll
    for (int m = 0; m < MT; ++m) {
      acc[m][0] = (floatx4){0.f, 0.f, 0.f, 0.f};
      acc[m][1] = (floatx4){0.f, 0.f, 0.f, 0.f};
    }
#pragma unroll
    for (int m = 0; m < MT; ++m) {
      const _Float16* arow = inb + (m * 16 + l15) * STRIDE + quad * 8;
#pragma unroll
      for (int ks = 0; ks < 8; ++ks) {
        half8 a = *(const half8*)(arow + ks * 32);
        acc[m][0] = __builtin_amdgcn_mfma_f32_16x16x32_f16(a, Wf[0][ks], acc[m][0], 0, 0, 0);
        acc[m][1] = __builtin_amdgcn_mfma_f32_16x16x32_f16(a, Wf[1][ks], acc[m][1], 0, 0, 0);
      }
    }
  }

  const int mrow = quad * 4;
#pragma unroll
  for (int m = 0; m < MT; ++m)
#pragma unroll
    for (int i = 0; i < 2; ++i) {
      const int col = (nbase + i) * 16 + l15;
#pragma unroll
      for (int r = 0; r < 4; ++r) {
        const int node = m * 16 + mrow + r;
        if (node < MOUT) {
          float v = fast_tanh(acc[m][i][r] + bias[i]);
          outb[(node >> 1) * STRIDE + (node & 1) * 128 + col] = (_Float16)v;
        }
      }
    }
}

__global__ __launch_bounds__(256, 3)   // cap 80 (proven no-spill); residency LDS-bound at 4/CU
void tree_kernel(const int* __restrict__ tokens,
                 const float* __restrict__ embedding,
                 const float* __restrict__ W_tree,
                 const float* __restrict__ b_tree,
                 const float* __restrict__ W_cls,
                 const float* __restrict__ b_cls,
                 float* __restrict__ out)
{
  __shared__ __align__(16) _Float16 bufA[32 * STRIDE];   // leaf halves / L1,L3,L5 outs (16.9 KB)
  __shared__ __align__(16) _Float16 bufB[32 * STRIDE];   // L0a+L0b outs / L2 out (16.9 KB)
  __shared__ __align__(16) _Float16 bufC[4 * STRIDE];    // pair stash: L4 outs (2.1 KB)
  __shared__ float wavepart[4][2][3];                    // classifier partials (96 B)

  const int tid  = threadIdx.x;
  const int wid  = tid >> 6;
  const int lane = tid & 63;
  const int l15  = lane & 15;
  const int quad = lane >> 4;
  const int nbase = wid * 2;               // this wave's n-tile base (features [32*wid,32*wid+32))
  const int row  = tid & 31;               // gather destination row (32-row half)
  const int seg  = tid >> 5;               // gather leaf/feature-quarter segment (0..7)
  const int leafq = 2 * row + (seg >> 2);  // leaf index within a 64-leaf half

  // ---- stage this wave's 2 n-tiles of W_tree as B-fragments (64 VGPR) ----
  // B[k][n] = W_tree[e=n][h=k]  (einsum 'bnh,eh->bne' => out = comb @ W^T)
  half8 Wf[2][8];
#pragma unroll
  for (int i = 0; i < 2; ++i) {
    const int e = (nbase + i) * 16 + l15;
#pragma unroll
    for (int ks = 0; ks < 8; ++ks) {
      const int k = ks * 32 + quad * 8;
      const float4* p = (const float4*)(W_tree + e * 256 + k);
      float4 lo = p[0], hi = p[1];
      half8 f;
      f[0] = (_Float16)lo.x; f[1] = (_Float16)lo.y; f[2] = (_Float16)lo.z; f[3] = (_Float16)lo.w;
      f[4] = (_Float16)hi.x; f[5] = (_Float16)hi.y; f[6] = (_Float16)hi.z; f[7] = (_Float16)hi.w;
      Wf[i][ks] = f;
    }
  }
  float bias[2];
#pragma unroll
  for (int i = 0; i < 2; ++i) bias[i] = b_tree[(nbase + i) * 16 + l15];

  // classifier weights for this lane's 2 columns: loop-invariant (6 VGPR)
  float wc[2][3];
#pragma unroll
  for (int i = 0; i < 2; ++i) {
    const int col = (nbase + i) * 16 + l15;
#pragma unroll
    for (int o = 0; o < 3; ++o) wc[i][o] = W_cls[o * 128 + col];
  }

  int tokCur = tokens[(2 * blockIdx.x) * 128 + leafq];   // preloaded: first pair s0 half-a

#pragma unroll 1
  for (int p = blockIdx.x; p < NPAIR; p += gridDim.x) {
    int pn = p + gridDim.x;
    if (pn >= NPAIR) pn = p;               // last iteration: harmless self-reload
    const int s0 = 2 * p, s1 = 2 * p + 1;

    // ================= s0 =================
    gather_half(tokCur, embedding, bufA, row, seg);            // ga: leaves 0-63 -> rows 0-31
    const int tokH2 = tokens[s0 * 128 + 64 + leafq];           // preload half-b token
    __syncthreads();
    level_std<2, 32>(bufA, bufB, Wf, bias, nbase, l15, quad);  // L0a: nodes 0-31 -> bufB 0-15
    __syncthreads();
    gather_half(tokH2, embedding, bufA, row, seg);             // gb: leaves 64-127 -> rows 0-31
    const int tokS1 = tokens[s1 * 128 + leafq];                // preload s1 half-a token
    __syncthreads();
    level_std<2, 32>(bufA, bufB + 16 * STRIDE,                 // L0b: nodes 32-63 -> bufB 16-31
                     Wf, bias, nbase, l15, quad);
    __syncthreads();
    level_std<2, 32>(bufB, bufA, Wf, bias, nbase, l15, quad);  // L1: bufB 0-31 -> bufA 0-15
    __syncthreads();
    level_std<1, 16>(bufA, bufB, Wf, bias, nbase, l15, quad);  // L2: bufA 0-15 -> bufB 0-7
    __syncthreads();
    level_std<1,  8>(bufB, bufA, Wf, bias, nbase, l15, quad);  // L3: bufB 0-7 -> bufA 0-3
    __syncthreads();
    level_std<1,  4>(bufA, bufC, Wf, bias, nbase, l15, quad);  // L4 -> bufC rows 0-1
    __syncthreads();

    // ================= s1 =================
    gather_half(tokS1, embedding, bufA, row, seg);             // ga
    const int tokS1b = tokens[s1 * 128 + 64 + leafq];          // preload half-b token
    __syncthreads();
    level_std<2, 32>(bufA, bufB, Wf, bias, nbase, l15, quad);  // L0a
    __syncthreads();
    gather_half(tokS1b, embedding, bufA, row, seg);            // gb
    tokCur = tokens[(2 * pn) * 128 + leafq];                   // preload next-pair s0 half-a
    __syncthreads();
    level_std<2, 32>(bufA, bufB + 16 * STRIDE, Wf, bias, nbase, l15, quad);  // L0b
    __syncthreads();
    level_std<2, 32>(bufB, bufA, Wf, bias, nbase, l15, quad);  // L1
    __syncthreads();
    level_std<1, 16>(bufA, bufB, Wf, bias, nbase, l15, quad);  // L2
    __syncthreads();
    level_std<1,  8>(bufB, bufA, Wf, bias, nbase, l15, quad);  // L3
    __syncthreads();
    level_std<1,  4>(bufA, bufC + 2 * STRIDE, Wf, bias, nbase, l15, quad); // L4 -> rows 2-3
    __syncthreads();

    // ---- batched L5: bufC rows 0-3 -> bufA rows 0-1 (dead after L4) ----
    {
      const int rclamp = l15 < 4 ? l15 : 3;          // bufC bounds; rows>=4 discarded
      floatx4 acc[2];
      mfma_k256(bufC + rclamp * STRIDE + quad * 8, Wf, acc);
      const int mrow = quad * 4;
#pragma unroll
      for (int i = 0; i < 2; ++i) {
        const int col = (nbase + i) * 16 + l15;
#pragma unroll
        for (int r = 0; r < 4; ++r) {
          const int mr = mrow + r;                   // mr<4 valid: sample mr>>1, node mr&1
          if (mr < 4) {
            float v = fast_tanh(acc[i][r] + bias[i]);
            bufA[(mr >> 1) * STRIDE + (mr & 1) * 128 + col] = (_Float16)v;
          }
        }
      }
    }
    __syncthreads();

    // ---- batched L6 + classifier partials from registers ----
    {
      floatx4 acc[2];
      mfma_k256(bufA + l15 * STRIDE + quad * 8, Wf, acc);  // rows 0-1 valid = roots s0,s1
      float part[2][3] = {{0.f, 0.f, 0.f}, {0.f, 0.f, 0.f}};
      if (quad == 0) {
#pragma unroll
        for (int i = 0; i < 2; ++i) {
#pragma unroll
          for (int rr = 0; rr < 2; ++rr) {           // rr = sample
            float v = fast_tanh(acc[i][rr] + bias[i]);
#pragma unroll
            for (int o = 0; o < 3; ++o) part[rr][o] = fmaf(v, wc[i][o], part[rr][o]);
          }
        }
      }
#pragma unroll
      for (int rr = 0; rr < 2; ++rr) {
#pragma unroll
        for (int o = 0; o < 3; ++o) {
          float v = part[rr][o];                     // nonzero only in quad-0 lanes
          v += __shfl_down(v, 8);
          v += __shfl_down(v, 4);
          v += __shfl_down(v, 2);
          v += __shfl_down(v, 1);
          if (lane == 0) wavepart[wid][rr][o] = v;
        }
      }
    }
    __syncthreads();
    if (tid < 6) {
      const int rr = tid / 3, o = tid - 3 * rr;
      float v = wavepart[0][rr][o] + wavepart[1][rr][o]
              + wavepart[2][rr][o] + wavepart[3][rr][o];
      out[(2 * p + rr) * 3 + o] = v + b_cls[o];
    }
    // next pair's ga overwrites bufA rows 0-31: L6's bufA reads completed before the
    // wavepart barrier; wavepart next written 17 barriers later -> safe.
  }
}

extern "C" void kernel_launch(void* const* d_in, const int* in_sizes, int n_in,
                              void* d_out, int out_size, void* d_ws, size_t ws_size,
                              hipStream_t stream) {
  const int*   tokens    = (const int*)d_in[0];
  const float* embedding = (const float*)d_in[1];
  const float* W_tree    = (const float*)d_in[2];
  const float* b_tree    = (const float*)d_in[3];
  const float* W_cls     = (const float*)d_in[4];
  const float* b_cls     = (const float*)d_in[5];
  float* out = (float*)d_out;

  dim3 grid(1024), block(256);   // 4 blocks/CU x 256 CUs x exactly 2 pairs: balanced rounds
  tree_kernel<<<grid, block, 0, stream>>>(tokens, embedding, W_tree, b_tree, W_cls, b_cls, out);
}